// Round 7
// baseline (1277.195 us; speedup 1.0000x reference)
//
#include <hip/hip_runtime.h>

#define N_USERS 100000
#define N_ITEMS 50000
#define N_NODES 150000
#define DIM 64
#define RDIM 32
#define NNZ_E 4800000
#define EMB_TOT (N_NODES * DIM)          // 9,600,000 floats
#define RPB 128                           // rows per bucket
#define NB ((N_NODES + RPB - 1) / RPB)    // 1172 buckets
#define BPART 128                         // partition blocks
#define TPART 1024                        // partition threads/block

// ---------------------------------------------------------------------------
// init: ego = concat(user, item); acc(d_out) = same
// ---------------------------------------------------------------------------
__global__ __launch_bounds__(256) void k_init(const float4* __restrict__ ue,
                                              const float4* __restrict__ ie,
                                              float4* __restrict__ ego,
                                              float4* __restrict__ acc) {
    int i = blockIdx.x * 256 + threadIdx.x;
    if (i >= EMB_TOT / 4) return;
    const int USER4 = N_USERS * DIM / 4;
    float4 v = (i < USER4) ? ue[i] : ie[i - USER4];
    ego[i] = v;
    acc[i] = v;
}

// ---------------------------------------------------------------------------
// partition 1: per-block bucket histogram (LDS, no global atomics)
// ---------------------------------------------------------------------------
__global__ __launch_bounds__(TPART) void k_hist(const int* __restrict__ rows,
                                                int* __restrict__ hist) {
    __shared__ int h[NB];
    for (int i = threadIdx.x; i < NB; i += TPART) h[i] = 0;
    __syncthreads();
    for (int e = blockIdx.x * TPART + threadIdx.x; e < NNZ_E; e += BPART * TPART)
        atomicAdd(&h[rows[e] >> 7], 1);
    __syncthreads();
    for (int i = threadIdx.x; i < NB; i += TPART)
        hist[blockIdx.x * NB + i] = h[i];
}

// ---------------------------------------------------------------------------
// partition 2a: bucket totals (column sums of hist)
// ---------------------------------------------------------------------------
__global__ __launch_bounds__(256) void k_btot(const int* __restrict__ hist,
                                              int* __restrict__ btot) {
    int b = blockIdx.x * 256 + threadIdx.x;
    if (b >= NB) return;
    int s = 0;
    for (int blk = 0; blk < BPART; ++blk) s += hist[blk * NB + b];
    btot[b] = s;
}

// ---------------------------------------------------------------------------
// partition 2b: exclusive scan of bucket totals -> base[NB+1]; rs sentinel
// ---------------------------------------------------------------------------
__global__ __launch_bounds__(1024) void k_bsum(const int* __restrict__ btot,
                                               int* __restrict__ base,
                                               int* __restrict__ rs) {
    __shared__ int sc[2048];
    int t = threadIdx.x;
    sc[t]        = (t < NB) ? btot[t] : 0;
    sc[t + 1024] = (t + 1024 < NB) ? btot[t + 1024] : 0;
    __syncthreads();
    for (int off = 1; off < 2048; off <<= 1) {
        int v1 = (t >= off) ? sc[t - off] : 0;
        int v2 = (t + 1024 >= off) ? sc[t + 1024 - off] : 0;
        __syncthreads();
        sc[t] += v1;
        sc[t + 1024] += v2;
        __syncthreads();
    }
    if (t < NB)        base[t] = (t == 0) ? 0 : sc[t - 1];
    if (t + 1024 < NB) base[t + 1024] = sc[t + 1023];
    if (t == 0) { base[NB] = NNZ_E; rs[N_NODES] = NNZ_E; }
}

// ---------------------------------------------------------------------------
// partition 2c: convert hist counts -> per-(block,bucket) starting offsets
// ---------------------------------------------------------------------------
__global__ __launch_bounds__(256) void k_off(int* __restrict__ hist,
                                             const int* __restrict__ base) {
    int b = blockIdx.x * 256 + threadIdx.x;
    if (b >= NB) return;
    int run = base[b];
    for (int blk = 0; blk < BPART; ++blk) {
        int c = hist[blk * NB + b];
        hist[blk * NB + b] = run;
        run += c;
    }
}

// ---------------------------------------------------------------------------
// partition 3: scatter edges into bucket-contiguous tmp (LDS cursors).
// payload: x = (row_local<<18) | col (7b + 18b), y = bits(val)
// ---------------------------------------------------------------------------
__global__ __launch_bounds__(TPART) void k_part(const int* __restrict__ rows,
                                                const int* __restrict__ cols,
                                                const float* __restrict__ vals,
                                                const int* __restrict__ hist,
                                                uint2* __restrict__ tmp) {
    __shared__ int cur[NB];
    for (int i = threadIdx.x; i < NB; i += TPART)
        cur[i] = hist[blockIdx.x * NB + i];
    __syncthreads();
    for (int e = blockIdx.x * TPART + threadIdx.x; e < NNZ_E; e += BPART * TPART) {
        int r = rows[e];
        int b = r >> 7;
        int pos = atomicAdd(&cur[b], 1);
        tmp[pos] = make_uint2(((unsigned)(r & 127) << 18) | (unsigned)cols[e],
                              __float_as_uint(vals[e]));
    }
}

// ---------------------------------------------------------------------------
// partition 4: within-bucket counting sort -> exact CSR edges + rs.
// ---------------------------------------------------------------------------
__global__ __launch_bounds__(256) void k_sortbkt(const uint2* __restrict__ tmp,
                                                 const int* __restrict__ base,
                                                 uint2* __restrict__ edges,
                                                 int* __restrict__ rs) {
    int b = blockIdx.x;
    int gbase = base[b];
    int nE = base[b + 1] - gbase;
    int nrows = N_NODES - b * RPB;
    if (nrows > RPB) nrows = RPB;

    __shared__ int cnt[RPB];
    __shared__ int sc[RPB];
    int t = threadIdx.x;
    if (t < RPB) cnt[t] = 0;
    __syncthreads();
    for (int i = t; i < nE; i += 256)
        atomicAdd(&cnt[tmp[gbase + i].x >> 18], 1);
    __syncthreads();
    if (t < RPB) sc[t] = cnt[t];
    __syncthreads();
    for (int off = 1; off < RPB; off <<= 1) {
        int v = 0;
        if (t < RPB && t >= off) v = sc[t - off];
        __syncthreads();
        if (t < RPB) sc[t] += v;
        __syncthreads();
    }
    if (t < RPB) {
        int excl = (t == 0) ? 0 : sc[t - 1];
        if (t < nrows) rs[b * RPB + t] = gbase + excl;
        cnt[t] = excl;          // reuse as scatter cursor
    }
    __syncthreads();
    for (int i = t; i < nE; i += 256) {
        uint2 u = tmp[gbase + i];
        int rl = u.x >> 18;
        int p = atomicAdd(&cnt[rl], 1);
        edges[gbase + p] = make_uint2(u.x & 0x3FFFFu, u.y);
    }
}

// ---------------------------------------------------------------------------
// partition 5: sort each row's edges by column (64-lane bitonic, in place).
// Makes concurrent waves sweep x[] in ascending address order -> L2 locality.
// Tie-safe: sort key = (col<<6)|lane (unique per lane).
// ---------------------------------------------------------------------------
__global__ __launch_bounds__(256) void k_sortcol(uint2* __restrict__ edges,
                                                 const int* __restrict__ rs) {
    int wid  = (blockIdx.x * 256 + threadIdx.x) >> 6;
    int lane = threadIdx.x & 63;
    if (wid >= N_NODES) return;
    int start = rs[wid];
    int end   = rs[wid + 1];
    for (int base = start; base < end; base += 64) {
        int n = end - base;
        if (n > 64) n = 64;
        unsigned skey = 0xFFFFFF00u | (unsigned)lane;   // unique sentinel
        unsigned val  = 0u;
        if (lane < n) {
            uint2 u = edges[base + lane];
            skey = (u.x << 6) | (unsigned)lane;          // col:18b | lane:6b
            val  = u.y;
        }
        #pragma unroll
        for (int k = 2; k <= 64; k <<= 1) {
            #pragma unroll
            for (int j = k >> 1; j > 0; j >>= 1) {
                unsigned pk = __shfl_xor(skey, j);
                unsigned pv = __shfl_xor(val, j);
                bool upper   = (lane & j) != 0;
                bool asc     = (lane & k) == 0;          // ascending block
                bool keepMin = (asc != upper);
                bool take    = (pk < skey) == keepMin;   // keys unique -> safe
                if (take) { skey = pk; val = pv; }
            }
        }
        if (lane < n) edges[base + lane] = make_uint2(skey >> 6, val);
    }
}

// ---------------------------------------------------------------------------
// CSR SpMM, one wave per row, lane = dim. No atomics; fused acc += y.
// ---------------------------------------------------------------------------
__global__ __launch_bounds__(256) void k_spmm_csr(const uint2* __restrict__ edges,
                                                  const int* __restrict__ rs,
                                                  const float* __restrict__ x,
                                                  float* __restrict__ y,
                                                  float* __restrict__ acc) {
    int wid  = (blockIdx.x * 256 + threadIdx.x) >> 6;
    int lane = threadIdx.x & 63;
    if (wid >= N_NODES) return;
    int start = rs[wid];
    int end   = rs[wid + 1];
    float s = 0.0f;
    for (int base = start; base < end; base += 64) {
        int n = end - base;
        if (n > 64) n = 64;
        uint2 ev = (lane < n) ? edges[base + lane] : make_uint2(0u, 0u);
        int   ec = (int)ev.x;
        float evv = __uint_as_float(ev.y);
        #pragma unroll 4
        for (int j = 0; j < n; ++j) {
            int   c = __shfl(ec, j);
            float v = __shfl(evv, j);
            s += v * x[(c << 6) + lane];      // 32-bit offset: < 9.6M
        }
    }
    int o = (wid << 6) + lane;                 // < 9.6M, 32-bit safe
    y[o] = s;
    acc[o] += s;
}

// ---------------------------------------------------------------------------
__global__ void k_zero_loss(float* p) {
    if (blockIdx.x == 0 && threadIdx.x == 0) *p = 0.0f;
}

// ---------------------------------------------------------------------------
// final: per-row  e = acc/4 ; h = W1 e + b1 ; g = W2 h + b2 ;
//        out_row = g (in place over acc) ; loss += ||g - e||^2
// ---------------------------------------------------------------------------
__global__ __launch_bounds__(256) void k_mlp_loss(float* __restrict__ out,
                                                  const float* __restrict__ w1,
                                                  const float* __restrict__ b1,
                                                  const float* __restrict__ w2,
                                                  const float* __restrict__ b2,
                                                  float* __restrict__ loss) {
    __shared__ float sw1[RDIM][DIM];
    __shared__ float sw2[DIM][RDIM];
    __shared__ float sb1[RDIM];
    __shared__ float sb2[DIM];

    for (int i = threadIdx.x; i < RDIM * DIM; i += 256) sw1[i / DIM][i % DIM] = w1[i];
    for (int i = threadIdx.x; i < DIM * RDIM; i += 256) sw2[i / RDIM][i % RDIM] = w2[i];
    if (threadIdx.x < RDIM) sb1[threadIdx.x] = b1[threadIdx.x];
    if (threadIdx.x < DIM)  sb2[threadIdx.x] = b2[threadIdx.x];
    __syncthreads();

    int r = blockIdx.x * 256 + threadIdx.x;
    float lsum = 0.0f;
    if (r < N_NODES) {
        float e[DIM];
        float4* rowp = (float4*)(out + (long long)r * DIM);
        #pragma unroll
        for (int q = 0; q < DIM / 4; ++q) {
            float4 v = rowp[q];
            e[4 * q + 0] = v.x * 0.25f;
            e[4 * q + 1] = v.y * 0.25f;
            e[4 * q + 2] = v.z * 0.25f;
            e[4 * q + 3] = v.w * 0.25f;
        }
        float h[RDIM];
        #pragma unroll
        for (int j = 0; j < RDIM; ++j) {
            float s = sb1[j];
            #pragma unroll
            for (int d = 0; d < DIM; ++d) s += sw1[j][d] * e[d];
            h[j] = s;
        }
        #pragma unroll
        for (int q = 0; q < DIM / 4; ++q) {
            float g[4];
            #pragma unroll
            for (int m = 0; m < 4; ++m) {
                int k = 4 * q + m;
                float s = sb2[k];
                #pragma unroll
                for (int j = 0; j < RDIM; ++j) s += sw2[k][j] * h[j];
                g[m] = s;
                float df = s - e[k];
                lsum += df * df;
            }
            float4 v;
            v.x = g[0]; v.y = g[1]; v.z = g[2]; v.w = g[3];
            rowp[q] = v;
        }
    }

    #pragma unroll
    for (int off = 32; off > 0; off >>= 1) lsum += __shfl_down(lsum, off);
    __shared__ float wsum[4];
    if ((threadIdx.x & 63) == 0) wsum[threadIdx.x >> 6] = lsum;
    __syncthreads();
    if (threadIdx.x == 0) {
        atomicAdd(loss, wsum[0] + wsum[1] + wsum[2] + wsum[3]);
    }
}

// ---------------------------------------------------------------------------
extern "C" void kernel_launch(void* const* d_in, const int* in_sizes, int n_in,
                              void* d_out, int out_size, void* d_ws, size_t ws_size,
                              hipStream_t stream) {
    const int*   rows = (const int*)d_in[0];
    const int*   cols = (const int*)d_in[1];
    const float* vals = (const float*)d_in[2];
    const float* ue   = (const float*)d_in[3];
    const float* ie   = (const float*)d_in[4];
    const float* w1   = (const float*)d_in[5];
    const float* b1   = (const float*)d_in[6];
    const float* w2   = (const float*)d_in[7];
    const float* b2   = (const float*)d_in[8];
    float* out = (float*)d_out;

    // workspace layout (~116.5 MB). tmp aliases egoB: tmp is dead before
    // spmm layer-1 writes egoB.
    float* egoA  = (float*)d_ws;                    // 38.4 MB
    float* egoB  = egoA + EMB_TOT;                  // 38.4 MB (aliased by tmp)
    uint2* tmp   = (uint2*)egoB;                    // NNZ_E * 8B = 38.4 MB
    uint2* edges = (uint2*)(egoB + EMB_TOT);        // 38.4 MB
    int*   hist  = (int*)(edges + NNZ_E);           // BPART*NB = 600 KB
    int*   btot  = hist + BPART * NB;               // NB
    int*   base  = btot + NB;                       // NB+1
    int*   rs    = base + NB + 1;                   // N_NODES+1

    const int VEC_BLOCKS = (EMB_TOT / 4 + 255) / 256;   // 9375

    // ---- CSR build: deterministic two-level partition, no global atomics ----
    k_hist<<<BPART, TPART, 0, stream>>>(rows, hist);
    k_btot<<<(NB + 255) / 256, 256, 0, stream>>>(hist, btot);
    k_bsum<<<1, 1024, 0, stream>>>(btot, base, rs);
    k_off<<<(NB + 255) / 256, 256, 0, stream>>>(hist, base);
    k_part<<<BPART, TPART, 0, stream>>>(rows, cols, vals, hist, tmp);
    k_sortbkt<<<NB, 256, 0, stream>>>(tmp, base, edges, rs);
    k_sortcol<<<(N_NODES * 64 + 255) / 256, 256, 0, stream>>>(edges, rs);

    k_init<<<VEC_BLOCKS, 256, 0, stream>>>((const float4*)ue, (const float4*)ie,
                                           (float4*)egoA, (float4*)out);

    // ---- 3 propagation layers, no atomics, fused acc += ----
    float* cur = egoA;
    float* nxt = egoB;
    for (int l = 0; l < 3; ++l) {
        k_spmm_csr<<<(N_NODES * 64 + 255) / 256, 256, 0, stream>>>(edges, rs, cur, nxt, out);
        float* t = cur; cur = nxt; nxt = t;
    }

    k_zero_loss<<<1, 64, 0, stream>>>(out + EMB_TOT);
    k_mlp_loss<<<(N_NODES + 255) / 256, 256, 0, stream>>>(out, w1, b1, w2, b2,
                                                          out + EMB_TOT);
}

// Round 11
// 1154.698 us; speedup vs baseline: 1.1061x; 1.1061x over previous
//
#include <hip/hip_runtime.h>

#define N_USERS 100000
#define N_ITEMS 50000
#define N_NODES 150000
#define DIM 64
#define RDIM 32
#define NNZ_E 4800000
#define EMB_TOT (N_NODES * DIM)          // 9,600,000 elems
#define RPB 128                           // rows per bucket
#define NB ((N_NODES + RPB - 1) / RPB)    // 1172 buckets
#define BPART 128                         // partition blocks
#define TPART 1024                        // partition threads/block

// bf16 helpers (RNE)
__device__ __forceinline__ unsigned short f2bf(float f) {
    unsigned u = __float_as_uint(f);
    u += 0x7FFFu + ((u >> 16) & 1u);
    return (unsigned short)(u >> 16);
}
__device__ __forceinline__ float bf2f(unsigned short b) {
    return __uint_as_float(((unsigned)b) << 16);
}

// ---------------------------------------------------------------------------
// init: ego0_bf16 = concat(user, item) rounded to bf16
// ---------------------------------------------------------------------------
__global__ __launch_bounds__(256) void k_init16(const float4* __restrict__ ue,
                                                const float4* __restrict__ ie,
                                                ushort4* __restrict__ ego) {
    int i = blockIdx.x * 256 + threadIdx.x;           // over EMB_TOT/4
    if (i >= EMB_TOT / 4) return;
    const int USER4 = N_USERS * DIM / 4;
    float4 v = (i < USER4) ? ue[i] : ie[i - USER4];
    ushort4 o;
    o.x = f2bf(v.x); o.y = f2bf(v.y); o.z = f2bf(v.z); o.w = f2bf(v.w);
    ego[i] = o;
}

// ---------------------------------------------------------------------------
// partition 1: per-block bucket histogram (LDS, no global atomics)
// ---------------------------------------------------------------------------
__global__ __launch_bounds__(TPART) void k_hist(const int* __restrict__ rows,
                                                int* __restrict__ hist) {
    __shared__ int h[NB];
    for (int i = threadIdx.x; i < NB; i += TPART) h[i] = 0;
    __syncthreads();
    for (int e = blockIdx.x * TPART + threadIdx.x; e < NNZ_E; e += BPART * TPART)
        atomicAdd(&h[rows[e] >> 7], 1);
    __syncthreads();
    for (int i = threadIdx.x; i < NB; i += TPART)
        hist[blockIdx.x * NB + i] = h[i];
}

// ---------------------------------------------------------------------------
// partition 2a: bucket totals (column sums of hist)
// ---------------------------------------------------------------------------
__global__ __launch_bounds__(256) void k_btot(const int* __restrict__ hist,
                                              int* __restrict__ btot) {
    int b = blockIdx.x * 256 + threadIdx.x;
    if (b >= NB) return;
    int s = 0;
    for (int blk = 0; blk < BPART; ++blk) s += hist[blk * NB + b];
    btot[b] = s;
}

// ---------------------------------------------------------------------------
// partition 2b: exclusive scan of bucket totals -> base[NB+1]; rs sentinel
// ---------------------------------------------------------------------------
__global__ __launch_bounds__(1024) void k_bsum(const int* __restrict__ btot,
                                               int* __restrict__ base,
                                               int* __restrict__ rs) {
    __shared__ int sc[2048];
    int t = threadIdx.x;
    sc[t]        = (t < NB) ? btot[t] : 0;
    sc[t + 1024] = (t + 1024 < NB) ? btot[t + 1024] : 0;
    __syncthreads();
    for (int off = 1; off < 2048; off <<= 1) {
        int v1 = (t >= off) ? sc[t - off] : 0;
        int v2 = (t + 1024 >= off) ? sc[t + 1024 - off] : 0;
        __syncthreads();
        sc[t] += v1;
        sc[t + 1024] += v2;
        __syncthreads();
    }
    if (t < NB)        base[t] = (t == 0) ? 0 : sc[t - 1];
    if (t + 1024 < NB) base[t + 1024] = sc[t + 1023];
    if (t == 0) { base[NB] = NNZ_E; rs[N_NODES] = NNZ_E; }
}

// ---------------------------------------------------------------------------
// partition 2c: convert hist counts -> per-(block,bucket) starting offsets
// ---------------------------------------------------------------------------
__global__ __launch_bounds__(256) void k_off(int* __restrict__ hist,
                                             const int* __restrict__ base) {
    int b = blockIdx.x * 256 + threadIdx.x;
    if (b >= NB) return;
    int run = base[b];
    for (int blk = 0; blk < BPART; ++blk) {
        int c = hist[blk * NB + b];
        hist[blk * NB + b] = run;
        run += c;
    }
}

// ---------------------------------------------------------------------------
// partition 3: scatter edges into bucket-contiguous tmp (LDS cursors).
// payload: x = (row_local<<18) | col (7b + 18b), y = bits(val)
// ---------------------------------------------------------------------------
__global__ __launch_bounds__(TPART) void k_part(const int* __restrict__ rows,
                                                const int* __restrict__ cols,
                                                const float* __restrict__ vals,
                                                const int* __restrict__ hist,
                                                uint2* __restrict__ tmp) {
    __shared__ int cur[NB];
    for (int i = threadIdx.x; i < NB; i += TPART)
        cur[i] = hist[blockIdx.x * NB + i];
    __syncthreads();
    for (int e = blockIdx.x * TPART + threadIdx.x; e < NNZ_E; e += BPART * TPART) {
        int r = rows[e];
        int b = r >> 7;
        int pos = atomicAdd(&cur[b], 1);
        tmp[pos] = make_uint2(((unsigned)(r & 127) << 18) | (unsigned)cols[e],
                              __float_as_uint(vals[e]));
    }
}

// ---------------------------------------------------------------------------
// partition 4: within-bucket counting sort -> exact CSR edges + rs.
// ---------------------------------------------------------------------------
__global__ __launch_bounds__(256) void k_sortbkt(const uint2* __restrict__ tmp,
                                                 const int* __restrict__ base,
                                                 uint2* __restrict__ edges,
                                                 int* __restrict__ rs) {
    int b = blockIdx.x;
    int gbase = base[b];
    int nE = base[b + 1] - gbase;
    int nrows = N_NODES - b * RPB;
    if (nrows > RPB) nrows = RPB;

    __shared__ int cnt[RPB];
    __shared__ int sc[RPB];
    int t = threadIdx.x;
    if (t < RPB) cnt[t] = 0;
    __syncthreads();
    for (int i = t; i < nE; i += 256)
        atomicAdd(&cnt[tmp[gbase + i].x >> 18], 1);
    __syncthreads();
    if (t < RPB) sc[t] = cnt[t];
    __syncthreads();
    for (int off = 1; off < RPB; off <<= 1) {
        int v = 0;
        if (t < RPB && t >= off) v = sc[t - off];
        __syncthreads();
        if (t < RPB) sc[t] += v;
        __syncthreads();
    }
    if (t < RPB) {
        int excl = (t == 0) ? 0 : sc[t - 1];
        if (t < nrows) rs[b * RPB + t] = gbase + excl;
        cnt[t] = excl;          // reuse as scatter cursor
    }
    __syncthreads();
    for (int i = t; i < nE; i += 256) {
        uint2 u = tmp[gbase + i];
        int rl = u.x >> 18;
        int p = atomicAdd(&cnt[rl], 1);
        edges[gbase + p] = make_uint2(u.x & 0x3FFFFu, u.y);
    }
}

// ---------------------------------------------------------------------------
// CSR SpMM bf16->bf16: one wave per row, lane = dim. No atomics, no acc RMW.
// ---------------------------------------------------------------------------
__global__ __launch_bounds__(256) void k_spmm16(const uint2* __restrict__ edges,
                                                const int* __restrict__ rs,
                                                const unsigned short* __restrict__ x16,
                                                unsigned short* __restrict__ y16) {
    int wid  = (blockIdx.x * 256 + threadIdx.x) >> 6;
    int lane = threadIdx.x & 63;
    if (wid >= N_NODES) return;
    int start = rs[wid];
    int end   = rs[wid + 1];
    float s = 0.0f;
    for (int base = start; base < end; base += 64) {
        int n = end - base;
        if (n > 64) n = 64;
        uint2 ev = (lane < n) ? edges[base + lane] : make_uint2(0u, 0u);
        int   ec = (int)ev.x;
        float evv = __uint_as_float(ev.y);
        #pragma unroll 8
        for (int j = 0; j < n; ++j) {
            int   c = __shfl(ec, j);
            float v = __shfl(evv, j);
            s += v * bf2f(x16[(c << 6) + lane]);
        }
    }
    y16[(wid << 6) + lane] = f2bf(s);
}

// ---------------------------------------------------------------------------
__global__ void k_zero_loss(float* p) {
    if (blockIdx.x == 0 && threadIdx.x == 0) *p = 0.0f;
}

// ---------------------------------------------------------------------------
// final: per-row  e = (ego_f32 + s1 + s2 + s3)/4 ; h = W1 e + b1 ;
//        g = W2 h + b2 ; out_row = g ; loss += ||g - e||^2
// ---------------------------------------------------------------------------
__global__ __launch_bounds__(256) void k_mlp_loss(const float* __restrict__ ue,
                                                  const float* __restrict__ ie,
                                                  const unsigned short* __restrict__ s1,
                                                  const unsigned short* __restrict__ s2,
                                                  const unsigned short* __restrict__ s3,
                                                  float* __restrict__ out,
                                                  const float* __restrict__ w1,
                                                  const float* __restrict__ b1,
                                                  const float* __restrict__ w2,
                                                  const float* __restrict__ b2,
                                                  float* __restrict__ loss) {
    __shared__ float sw1[RDIM][DIM];
    __shared__ float sw2[DIM][RDIM];
    __shared__ float sb1[RDIM];
    __shared__ float sb2[DIM];

    for (int i = threadIdx.x; i < RDIM * DIM; i += 256) sw1[i / DIM][i % DIM] = w1[i];
    for (int i = threadIdx.x; i < DIM * RDIM; i += 256) sw2[i / RDIM][i % RDIM] = w2[i];
    if (threadIdx.x < RDIM) sb1[threadIdx.x] = b1[threadIdx.x];
    if (threadIdx.x < DIM)  sb2[threadIdx.x] = b2[threadIdx.x];
    __syncthreads();

    int r = blockIdx.x * 256 + threadIdx.x;
    float lsum = 0.0f;
    if (r < N_NODES) {
        const float* ego = (r < N_USERS) ? (ue + (size_t)r * DIM)
                                         : (ie + (size_t)(r - N_USERS) * DIM);
        float e[DIM];
        {
            const float4*  e4 = (const float4*)ego;
            const ushort4* p1 = (const ushort4*)(s1 + ((size_t)r << 6));
            const ushort4* p2 = (const ushort4*)(s2 + ((size_t)r << 6));
            const ushort4* p3 = (const ushort4*)(s3 + ((size_t)r << 6));
            #pragma unroll
            for (int q = 0; q < DIM / 4; ++q) {
                float4 v = e4[q];
                ushort4 a = p1[q], b = p2[q], c = p3[q];
                e[4 * q + 0] = 0.25f * (v.x + bf2f(a.x) + bf2f(b.x) + bf2f(c.x));
                e[4 * q + 1] = 0.25f * (v.y + bf2f(a.y) + bf2f(b.y) + bf2f(c.y));
                e[4 * q + 2] = 0.25f * (v.z + bf2f(a.z) + bf2f(b.z) + bf2f(c.z));
                e[4 * q + 3] = 0.25f * (v.w + bf2f(a.w) + bf2f(b.w) + bf2f(c.w));
            }
        }
        float h[RDIM];
        #pragma unroll
        for (int j = 0; j < RDIM; ++j) {
            float s = sb1[j];
            #pragma unroll
            for (int d = 0; d < DIM; ++d) s += sw1[j][d] * e[d];
            h[j] = s;
        }
        float4* rowp = (float4*)(out + ((size_t)r << 6));
        #pragma unroll
        for (int q = 0; q < DIM / 4; ++q) {
            float g[4];
            #pragma unroll
            for (int m = 0; m < 4; ++m) {
                int k = 4 * q + m;
                float s = sb2[k];
                #pragma unroll
                for (int j = 0; j < RDIM; ++j) s += sw2[k][j] * h[j];
                g[m] = s;
                float df = s - e[k];
                lsum += df * df;
            }
            float4 v;
            v.x = g[0]; v.y = g[1]; v.z = g[2]; v.w = g[3];
            rowp[q] = v;
        }
    }

    #pragma unroll
    for (int off = 32; off > 0; off >>= 1) lsum += __shfl_down(lsum, off);
    __shared__ float wsum[4];
    if ((threadIdx.x & 63) == 0) wsum[threadIdx.x >> 6] = lsum;
    __syncthreads();
    if (threadIdx.x == 0) {
        atomicAdd(loss, wsum[0] + wsum[1] + wsum[2] + wsum[3]);
    }
}

// ---------------------------------------------------------------------------
extern "C" void kernel_launch(void* const* d_in, const int* in_sizes, int n_in,
                              void* d_out, int out_size, void* d_ws, size_t ws_size,
                              hipStream_t stream) {
    const int*   rows = (const int*)d_in[0];
    const int*   cols = (const int*)d_in[1];
    const float* vals = (const float*)d_in[2];
    const float* ue   = (const float*)d_in[3];
    const float* ie   = (const float*)d_in[4];
    const float* w1   = (const float*)d_in[5];
    const float* b1   = (const float*)d_in[6];
    const float* w2   = (const float*)d_in[7];
    const float* b2   = (const float*)d_in[8];
    float* out = (float*)d_out;

    // workspace layout (~116 MB):
    //   A: 38.4 MB  -> s2 (19.2) + s3 (19.2)            [bf16 stages]
    //   B: 38.4 MB  -> partition tmp, then ego0 + s1    [aliased]
    //   C: 38.4 MB  -> edges
    unsigned short* regA = (unsigned short*)d_ws;              // EMB_TOT*2 shorts
    unsigned short* regB = regA + 2 * EMB_TOT;                 // EMB_TOT*2 shorts
    uint2* tmp   = (uint2*)regB;
    uint2* edges = (uint2*)(regB + 2 * EMB_TOT);               // 38.4 MB
    int*   hist  = (int*)(edges + NNZ_E);                      // BPART*NB
    int*   btot  = hist + BPART * NB;                          // NB
    int*   base  = btot + NB;                                  // NB+1
    int*   rs    = base + NB + 1;                              // N_NODES+1

    unsigned short* ego0 = regB;                 // 19.2 MB
    unsigned short* s1   = regB + EMB_TOT;       // 19.2 MB
    unsigned short* s2   = regA;                 // 19.2 MB
    unsigned short* s3   = regA + EMB_TOT;       // 19.2 MB

    const int VEC_BLOCKS  = (EMB_TOT / 4 + 255) / 256;   // 9375
    const int SPMM_BLOCKS = (N_NODES * 64 + 255) / 256;

    // ---- CSR build: deterministic two-level partition, no global atomics ----
    k_hist<<<BPART, TPART, 0, stream>>>(rows, hist);
    k_btot<<<(NB + 255) / 256, 256, 0, stream>>>(hist, btot);
    k_bsum<<<1, 1024, 0, stream>>>(btot, base, rs);
    k_off<<<(NB + 255) / 256, 256, 0, stream>>>(hist, base);
    k_part<<<BPART, TPART, 0, stream>>>(rows, cols, vals, hist, tmp);
    k_sortbkt<<<NB, 256, 0, stream>>>(tmp, base, edges, rs);

    // ---- ego0 (bf16) after tmp is dead ----
    k_init16<<<VEC_BLOCKS, 256, 0, stream>>>((const float4*)ue, (const float4*)ie,
                                             (ushort4*)ego0);

    // ---- 3 propagation layers, bf16 stages, no acc RMW ----
    k_spmm16<<<SPMM_BLOCKS, 256, 0, stream>>>(edges, rs, ego0, s1);
    k_spmm16<<<SPMM_BLOCKS, 256, 0, stream>>>(edges, rs, s1, s2);
    k_spmm16<<<SPMM_BLOCKS, 256, 0, stream>>>(edges, rs, s2, s3);

    k_zero_loss<<<1, 64, 0, stream>>>(out + EMB_TOT);
    k_mlp_loss<<<(N_NODES + 255) / 256, 256, 0, stream>>>(ue, ie, s1, s2, s3,
                                                          out, w1, b1, w2, b2,
                                                          out + EMB_TOT);
}

// Round 15
// 728.817 us; speedup vs baseline: 1.7524x; 1.5843x over previous
//
#include <hip/hip_runtime.h>

#define N_USERS 100000
#define N_ITEMS 50000
#define N_NODES 150000
#define DIM 64
#define RDIM 32
#define NNZ_E 4800000
#define EMB_TOT (N_NODES * DIM)          // 9,600,000 elems
#define RPB 128                           // rows per bucket
#define NB ((N_NODES + RPB - 1) / RPB)    // 1172 buckets
#define BPART 128                         // partition blocks
#define TPART 1024                        // partition threads/block

// bf16 helpers (RNE)
__device__ __forceinline__ unsigned short f2bf(float f) {
    unsigned u = __float_as_uint(f);
    u += 0x7FFFu + ((u >> 16) & 1u);
    return (unsigned short)(u >> 16);
}
__device__ __forceinline__ float bf2f(unsigned short b) {
    return __uint_as_float(((unsigned)b) << 16);
}

// ---------------------------------------------------------------------------
// init: ego0_bf16 = concat(user, item) rounded to bf16
// ---------------------------------------------------------------------------
__global__ __launch_bounds__(256) void k_init16(const float4* __restrict__ ue,
                                                const float4* __restrict__ ie,
                                                ushort4* __restrict__ ego) {
    int i = blockIdx.x * 256 + threadIdx.x;           // over EMB_TOT/4
    if (i >= EMB_TOT / 4) return;
    const int USER4 = N_USERS * DIM / 4;
    float4 v = (i < USER4) ? ue[i] : ie[i - USER4];
    ushort4 o;
    o.x = f2bf(v.x); o.y = f2bf(v.y); o.z = f2bf(v.z); o.w = f2bf(v.w);
    ego[i] = o;
}

// ---------------------------------------------------------------------------
// partition 1: per-block bucket histogram (LDS, no global atomics)
// ---------------------------------------------------------------------------
__global__ __launch_bounds__(TPART) void k_hist(const int* __restrict__ rows,
                                                int* __restrict__ hist) {
    __shared__ int h[NB];
    for (int i = threadIdx.x; i < NB; i += TPART) h[i] = 0;
    __syncthreads();
    for (int e = blockIdx.x * TPART + threadIdx.x; e < NNZ_E; e += BPART * TPART)
        atomicAdd(&h[rows[e] >> 7], 1);
    __syncthreads();
    for (int i = threadIdx.x; i < NB; i += TPART)
        hist[blockIdx.x * NB + i] = h[i];
}

// ---------------------------------------------------------------------------
// partition 2a: bucket totals (column sums of hist)
// ---------------------------------------------------------------------------
__global__ __launch_bounds__(256) void k_btot(const int* __restrict__ hist,
                                              int* __restrict__ btot) {
    int b = blockIdx.x * 256 + threadIdx.x;
    if (b >= NB) return;
    int s = 0;
    for (int blk = 0; blk < BPART; ++blk) s += hist[blk * NB + b];
    btot[b] = s;
}

// ---------------------------------------------------------------------------
// partition 2b: exclusive scan of bucket totals -> base[NB+1]; rs sentinel
// ---------------------------------------------------------------------------
__global__ __launch_bounds__(1024) void k_bsum(const int* __restrict__ btot,
                                               int* __restrict__ base,
                                               int* __restrict__ rs) {
    __shared__ int sc[2048];
    int t = threadIdx.x;
    sc[t]        = (t < NB) ? btot[t] : 0;
    sc[t + 1024] = (t + 1024 < NB) ? btot[t + 1024] : 0;
    __syncthreads();
    for (int off = 1; off < 2048; off <<= 1) {
        int v1 = (t >= off) ? sc[t - off] : 0;
        int v2 = (t + 1024 >= off) ? sc[t + 1024 - off] : 0;
        __syncthreads();
        sc[t] += v1;
        sc[t + 1024] += v2;
        __syncthreads();
    }
    if (t < NB)        base[t] = (t == 0) ? 0 : sc[t - 1];
    if (t + 1024 < NB) base[t + 1024] = sc[t + 1023];
    if (t == 0) { base[NB] = NNZ_E; rs[N_NODES] = NNZ_E; }
}

// ---------------------------------------------------------------------------
// partition 2c: convert hist counts -> per-(block,bucket) starting offsets
// ---------------------------------------------------------------------------
__global__ __launch_bounds__(256) void k_off(int* __restrict__ hist,
                                             const int* __restrict__ base) {
    int b = blockIdx.x * 256 + threadIdx.x;
    if (b >= NB) return;
    int run = base[b];
    for (int blk = 0; blk < BPART; ++blk) {
        int c = hist[blk * NB + b];
        hist[blk * NB + b] = run;
        run += c;
    }
}

// ---------------------------------------------------------------------------
// partition 3: scatter edges into bucket-contiguous tmp (LDS cursors).
// payload: x = (row_local<<18) | col (7b + 18b), y = bits(val)
// ---------------------------------------------------------------------------
__global__ __launch_bounds__(TPART) void k_part(const int* __restrict__ rows,
                                                const int* __restrict__ cols,
                                                const float* __restrict__ vals,
                                                const int* __restrict__ hist,
                                                uint2* __restrict__ tmp) {
    __shared__ int cur[NB];
    for (int i = threadIdx.x; i < NB; i += TPART)
        cur[i] = hist[blockIdx.x * NB + i];
    __syncthreads();
    for (int e = blockIdx.x * TPART + threadIdx.x; e < NNZ_E; e += BPART * TPART) {
        int r = rows[e];
        int b = r >> 7;
        int pos = atomicAdd(&cur[b], 1);
        tmp[pos] = make_uint2(((unsigned)(r & 127) << 18) | (unsigned)cols[e],
                              __float_as_uint(vals[e]));
    }
}

// ---------------------------------------------------------------------------
// partition 4: within-bucket counting sort -> exact CSR edges + rs.
// ---------------------------------------------------------------------------
__global__ __launch_bounds__(256) void k_sortbkt(const uint2* __restrict__ tmp,
                                                 const int* __restrict__ base,
                                                 uint2* __restrict__ edges,
                                                 int* __restrict__ rs) {
    int b = blockIdx.x;
    int gbase = base[b];
    int nE = base[b + 1] - gbase;
    int nrows = N_NODES - b * RPB;
    if (nrows > RPB) nrows = RPB;

    __shared__ int cnt[RPB];
    __shared__ int sc[RPB];
    int t = threadIdx.x;
    if (t < RPB) cnt[t] = 0;
    __syncthreads();
    for (int i = t; i < nE; i += 256)
        atomicAdd(&cnt[tmp[gbase + i].x >> 18], 1);
    __syncthreads();
    if (t < RPB) sc[t] = cnt[t];
    __syncthreads();
    for (int off = 1; off < RPB; off <<= 1) {
        int v = 0;
        if (t < RPB && t >= off) v = sc[t - off];
        __syncthreads();
        if (t < RPB) sc[t] += v;
        __syncthreads();
    }
    if (t < RPB) {
        int excl = (t == 0) ? 0 : sc[t - 1];
        if (t < nrows) rs[b * RPB + t] = gbase + excl;
        cnt[t] = excl;          // reuse as scatter cursor
    }
    __syncthreads();
    for (int i = t; i < nE; i += 256) {
        uint2 u = tmp[gbase + i];
        int rl = u.x >> 18;
        int p = atomicAdd(&cnt[rl], 1);
        edges[gbase + p] = make_uint2(u.x & 0x3FFFFu, u.y);
    }
}

// ---------------------------------------------------------------------------
// CSR SpMM bf16->bf16: one wave per row, lane = dim.
// Edge reads are WAVE-UNIFORM (readfirstlane-forced SGPR base) -> scalar
// s_load broadcast, no ds_bpermute. Per edge: ~1/4 merged s_load + 1 gather
// + cvt + fma.
// ---------------------------------------------------------------------------
__global__ __launch_bounds__(256) void k_spmm16(const uint2* __restrict__ edges,
                                                const int* __restrict__ rs,
                                                const unsigned short* __restrict__ x16,
                                                unsigned short* __restrict__ y16) {
    int wid  = (blockIdx.x * 256 + threadIdx.x) >> 6;
    int lane = threadIdx.x & 63;
    if (wid >= N_NODES) return;
    int start = __builtin_amdgcn_readfirstlane(rs[wid]);
    int end   = __builtin_amdgcn_readfirstlane(rs[wid + 1]);
    const unsigned short* xl = x16 + lane;
    float s = 0.0f;
    #pragma unroll 8
    for (int j = start; j < end; ++j) {
        uint2 e = edges[j];                    // uniform addr -> s_load bcast
        s += __uint_as_float(e.y) * bf2f(xl[(int)e.x << 6]);
    }
    y16[(wid << 6) + lane] = f2bf(s);
}

// ---------------------------------------------------------------------------
__global__ void k_zero_loss(float* p) {
    if (blockIdx.x == 0 && threadIdx.x == 0) *p = 0.0f;
}

// ---------------------------------------------------------------------------
// final: per-row  e = (ego_f32 + s1 + s2 + s3)/4 ; h = W1 e + b1 ;
//        g = W2 h + b2 ; out_row = g ; loss += ||g - e||^2
// ---------------------------------------------------------------------------
__global__ __launch_bounds__(256) void k_mlp_loss(const float* __restrict__ ue,
                                                  const float* __restrict__ ie,
                                                  const unsigned short* __restrict__ s1,
                                                  const unsigned short* __restrict__ s2,
                                                  const unsigned short* __restrict__ s3,
                                                  float* __restrict__ out,
                                                  const float* __restrict__ w1,
                                                  const float* __restrict__ b1,
                                                  const float* __restrict__ w2,
                                                  const float* __restrict__ b2,
                                                  float* __restrict__ loss) {
    __shared__ float sw1[RDIM][DIM];
    __shared__ float sw2[DIM][RDIM];
    __shared__ float sb1[RDIM];
    __shared__ float sb2[DIM];

    for (int i = threadIdx.x; i < RDIM * DIM; i += 256) sw1[i / DIM][i % DIM] = w1[i];
    for (int i = threadIdx.x; i < DIM * RDIM; i += 256) sw2[i / RDIM][i % RDIM] = w2[i];
    if (threadIdx.x < RDIM) sb1[threadIdx.x] = b1[threadIdx.x];
    if (threadIdx.x < DIM)  sb2[threadIdx.x] = b2[threadIdx.x];
    __syncthreads();

    int r = blockIdx.x * 256 + threadIdx.x;
    float lsum = 0.0f;
    if (r < N_NODES) {
        const float* ego = (r < N_USERS) ? (ue + (size_t)r * DIM)
                                         : (ie + (size_t)(r - N_USERS) * DIM);
        float e[DIM];
        {
            const float4*  e4 = (const float4*)ego;
            const ushort4* p1 = (const ushort4*)(s1 + ((size_t)r << 6));
            const ushort4* p2 = (const ushort4*)(s2 + ((size_t)r << 6));
            const ushort4* p3 = (const ushort4*)(s3 + ((size_t)r << 6));
            #pragma unroll
            for (int q = 0; q < DIM / 4; ++q) {
                float4 v = e4[q];
                ushort4 a = p1[q], b = p2[q], c = p3[q];
                e[4 * q + 0] = 0.25f * (v.x + bf2f(a.x) + bf2f(b.x) + bf2f(c.x));
                e[4 * q + 1] = 0.25f * (v.y + bf2f(a.y) + bf2f(b.y) + bf2f(c.y));
                e[4 * q + 2] = 0.25f * (v.z + bf2f(a.z) + bf2f(b.z) + bf2f(c.z));
                e[4 * q + 3] = 0.25f * (v.w + bf2f(a.w) + bf2f(b.w) + bf2f(c.w));
            }
        }
        float h[RDIM];
        #pragma unroll
        for (int j = 0; j < RDIM; ++j) {
            float s = sb1[j];
            #pragma unroll
            for (int d = 0; d < DIM; ++d) s += sw1[j][d] * e[d];
            h[j] = s;
        }
        float4* rowp = (float4*)(out + ((size_t)r << 6));
        #pragma unroll
        for (int q = 0; q < DIM / 4; ++q) {
            float g[4];
            #pragma unroll
            for (int m = 0; m < 4; ++m) {
                int k = 4 * q + m;
                float s = sb2[k];
                #pragma unroll
                for (int j = 0; j < RDIM; ++j) s += sw2[k][j] * h[j];
                g[m] = s;
                float df = s - e[k];
                lsum += df * df;
            }
            float4 v;
            v.x = g[0]; v.y = g[1]; v.z = g[2]; v.w = g[3];
            rowp[q] = v;
        }
    }

    #pragma unroll
    for (int off = 32; off > 0; off >>= 1) lsum += __shfl_down(lsum, off);
    __shared__ float wsum[4];
    if ((threadIdx.x & 63) == 0) wsum[threadIdx.x >> 6] = lsum;
    __syncthreads();
    if (threadIdx.x == 0) {
        atomicAdd(loss, wsum[0] + wsum[1] + wsum[2] + wsum[3]);
    }
}

// ---------------------------------------------------------------------------
extern "C" void kernel_launch(void* const* d_in, const int* in_sizes, int n_in,
                              void* d_out, int out_size, void* d_ws, size_t ws_size,
                              hipStream_t stream) {
    const int*   rows = (const int*)d_in[0];
    const int*   cols = (const int*)d_in[1];
    const float* vals = (const float*)d_in[2];
    const float* ue   = (const float*)d_in[3];
    const float* ie   = (const float*)d_in[4];
    const float* w1   = (const float*)d_in[5];
    const float* b1   = (const float*)d_in[6];
    const float* w2   = (const float*)d_in[7];
    const float* b2   = (const float*)d_in[8];
    float* out = (float*)d_out;

    // workspace layout (~116 MB):
    //   A: 38.4 MB  -> s2 (19.2) + s3 (19.2)            [bf16 stages]
    //   B: 38.4 MB  -> partition tmp, then ego0 + s1    [aliased]
    //   C: 38.4 MB  -> edges
    unsigned short* regA = (unsigned short*)d_ws;              // EMB_TOT*2 shorts
    unsigned short* regB = regA + 2 * EMB_TOT;                 // EMB_TOT*2 shorts
    uint2* tmp   = (uint2*)regB;
    uint2* edges = (uint2*)(regB + 2 * EMB_TOT);               // 38.4 MB
    int*   hist  = (int*)(edges + NNZ_E);                      // BPART*NB
    int*   btot  = hist + BPART * NB;                          // NB
    int*   base  = btot + NB;                                  // NB+1
    int*   rs    = base + NB + 1;                              // N_NODES+1

    unsigned short* ego0 = regB;                 // 19.2 MB
    unsigned short* s1   = regB + EMB_TOT;       // 19.2 MB
    unsigned short* s2   = regA;                 // 19.2 MB
    unsigned short* s3   = regA + EMB_TOT;       // 19.2 MB

    const int VEC_BLOCKS  = (EMB_TOT / 4 + 255) / 256;   // 9375
    const int SPMM_BLOCKS = (N_NODES * 64 + 255) / 256;

    // ---- CSR build: deterministic two-level partition, no global atomics ----
    k_hist<<<BPART, TPART, 0, stream>>>(rows, hist);
    k_btot<<<(NB + 255) / 256, 256, 0, stream>>>(hist, btot);
    k_bsum<<<1, 1024, 0, stream>>>(btot, base, rs);
    k_off<<<(NB + 255) / 256, 256, 0, stream>>>(hist, base);
    k_part<<<BPART, TPART, 0, stream>>>(rows, cols, vals, hist, tmp);
    k_sortbkt<<<NB, 256, 0, stream>>>(tmp, base, edges, rs);

    // ---- ego0 (bf16) after tmp is dead ----
    k_init16<<<VEC_BLOCKS, 256, 0, stream>>>((const float4*)ue, (const float4*)ie,
                                             (ushort4*)ego0);

    // ---- 3 propagation layers, bf16 stages, no acc RMW ----
    k_spmm16<<<SPMM_BLOCKS, 256, 0, stream>>>(edges, rs, ego0, s1);
    k_spmm16<<<SPMM_BLOCKS, 256, 0, stream>>>(edges, rs, s1, s2);
    k_spmm16<<<SPMM_BLOCKS, 256, 0, stream>>>(edges, rs, s2, s3);

    k_zero_loss<<<1, 64, 0, stream>>>(out + EMB_TOT);
    k_mlp_loss<<<(N_NODES + 255) / 256, 256, 0, stream>>>(ue, ie, s1, s2, s3,
                                                          out, w1, b1, w2, b2,
                                                          out + EMB_TOT);
}

// Round 16
// 683.459 us; speedup vs baseline: 1.8687x; 1.0664x over previous
//
#include <hip/hip_runtime.h>

#define N_USERS 100000
#define N_ITEMS 50000
#define N_NODES 150000
#define DIM 64
#define RDIM 32
#define NNZ_E 4800000
#define EMB_TOT (N_NODES * DIM)          // 9,600,000 elems
#define RPB 512                           // rows per bucket (9 bits)
#define NB ((N_NODES + RPB - 1) / RPB)    // 293 buckets
#define BPART 256                         // partition blocks (1 per CU)
#define TPART 1024                        // partition threads/block

// bf16 helpers (RNE)
__device__ __forceinline__ unsigned short f2bf(float f) {
    unsigned u = __float_as_uint(f);
    u += 0x7FFFu + ((u >> 16) & 1u);
    return (unsigned short)(u >> 16);
}
__device__ __forceinline__ float bf2f(unsigned short b) {
    return __uint_as_float(((unsigned)b) << 16);
}

// ---------------------------------------------------------------------------
// init: ego0_bf16 = concat(user, item) rounded to bf16
// ---------------------------------------------------------------------------
__global__ __launch_bounds__(256) void k_init16(const float4* __restrict__ ue,
                                                const float4* __restrict__ ie,
                                                ushort4* __restrict__ ego) {
    int i = blockIdx.x * 256 + threadIdx.x;           // over EMB_TOT/4
    if (i >= EMB_TOT / 4) return;
    const int USER4 = N_USERS * DIM / 4;
    float4 v = (i < USER4) ? ue[i] : ie[i - USER4];
    ushort4 o;
    o.x = f2bf(v.x); o.y = f2bf(v.y); o.z = f2bf(v.z); o.w = f2bf(v.w);
    ego[i] = o;
}

// ---------------------------------------------------------------------------
// partition 1: per-block bucket histogram (LDS, no global atomics)
// ---------------------------------------------------------------------------
__global__ __launch_bounds__(TPART) void k_hist(const int* __restrict__ rows,
                                                int* __restrict__ hist) {
    __shared__ int h[NB];
    for (int i = threadIdx.x; i < NB; i += TPART) h[i] = 0;
    __syncthreads();
    for (int e = blockIdx.x * TPART + threadIdx.x; e < NNZ_E; e += BPART * TPART)
        atomicAdd(&h[rows[e] >> 9], 1);
    __syncthreads();
    for (int i = threadIdx.x; i < NB; i += TPART)
        hist[blockIdx.x * NB + i] = h[i];
}

// ---------------------------------------------------------------------------
// partition 2a: bucket totals (column sums of hist)
// ---------------------------------------------------------------------------
__global__ __launch_bounds__(256) void k_btot(const int* __restrict__ hist,
                                              int* __restrict__ btot) {
    int b = blockIdx.x * 256 + threadIdx.x;
    if (b >= NB) return;
    int s = 0;
    for (int blk = 0; blk < BPART; ++blk) s += hist[blk * NB + b];
    btot[b] = s;
}

// ---------------------------------------------------------------------------
// partition 2b: exclusive scan of bucket totals -> base[NB+1]; rs sentinel
// (NB = 293 <= 1024, single-block scan)
// ---------------------------------------------------------------------------
__global__ __launch_bounds__(1024) void k_bsum(const int* __restrict__ btot,
                                               int* __restrict__ base,
                                               int* __restrict__ rs) {
    __shared__ int sc[1024];
    int t = threadIdx.x;
    sc[t] = (t < NB) ? btot[t] : 0;
    __syncthreads();
    for (int off = 1; off < 1024; off <<= 1) {
        int v = (t >= off) ? sc[t - off] : 0;
        __syncthreads();
        sc[t] += v;
        __syncthreads();
    }
    if (t < NB) base[t] = (t == 0) ? 0 : sc[t - 1];
    if (t == 0) { base[NB] = NNZ_E; rs[N_NODES] = NNZ_E; }
}

// ---------------------------------------------------------------------------
// partition 2c: convert hist counts -> per-(block,bucket) starting offsets
// ---------------------------------------------------------------------------
__global__ __launch_bounds__(256) void k_off(int* __restrict__ hist,
                                             const int* __restrict__ base) {
    int b = blockIdx.x * 256 + threadIdx.x;
    if (b >= NB) return;
    int run = base[b];
    for (int blk = 0; blk < BPART; ++blk) {
        int c = hist[blk * NB + b];
        hist[blk * NB + b] = run;
        run += c;
    }
}

// ---------------------------------------------------------------------------
// partition 3: scatter edges into bucket-contiguous tmp (LDS cursors).
// payload: x = (row_local<<18) | col (9b + 18b = 27b), y = bits(val)
// ---------------------------------------------------------------------------
__global__ __launch_bounds__(TPART) void k_part(const int* __restrict__ rows,
                                                const int* __restrict__ cols,
                                                const float* __restrict__ vals,
                                                const int* __restrict__ hist,
                                                uint2* __restrict__ tmp) {
    __shared__ int cur[NB];
    for (int i = threadIdx.x; i < NB; i += TPART)
        cur[i] = hist[blockIdx.x * NB + i];
    __syncthreads();
    for (int e = blockIdx.x * TPART + threadIdx.x; e < NNZ_E; e += BPART * TPART) {
        int r = rows[e];
        int b = r >> 9;
        int pos = atomicAdd(&cur[b], 1);
        tmp[pos] = make_uint2(((unsigned)(r & 511) << 18) | (unsigned)cols[e],
                              __float_as_uint(vals[e]));
    }
}

// ---------------------------------------------------------------------------
// partition 4: within-bucket counting sort -> exact CSR edges + rs.
// 512 rows/bucket, 512 threads; bucket window ~128KB, L2-resident.
// ---------------------------------------------------------------------------
__global__ __launch_bounds__(512) void k_sortbkt(const uint2* __restrict__ tmp,
                                                 const int* __restrict__ base,
                                                 uint2* __restrict__ edges,
                                                 int* __restrict__ rs) {
    int b = blockIdx.x;
    int gbase = base[b];
    int nE = base[b + 1] - gbase;
    int nrows = N_NODES - b * RPB;
    if (nrows > RPB) nrows = RPB;

    __shared__ int cnt[RPB];
    __shared__ int sc[RPB];
    int t = threadIdx.x;        // 0..511
    cnt[t] = 0;
    __syncthreads();
    for (int i = t; i < nE; i += 512)
        atomicAdd(&cnt[tmp[gbase + i].x >> 18], 1);
    __syncthreads();
    sc[t] = cnt[t];
    __syncthreads();
    for (int off = 1; off < RPB; off <<= 1) {
        int v = (t >= off) ? sc[t - off] : 0;
        __syncthreads();
        sc[t] += v;
        __syncthreads();
    }
    {
        int excl = (t == 0) ? 0 : sc[t - 1];
        if (t < nrows) rs[b * RPB + t] = gbase + excl;
        cnt[t] = excl;          // reuse as scatter cursor
    }
    __syncthreads();
    for (int i = t; i < nE; i += 512) {
        uint2 u = tmp[gbase + i];
        int rl = u.x >> 18;
        int p = atomicAdd(&cnt[rl], 1);
        edges[gbase + p] = make_uint2(u.x & 0x3FFFFu, u.y);
    }
}

// ---------------------------------------------------------------------------
// CSR SpMM bf16->bf16: one wave per row, lane = dim.
// Edge reads are WAVE-UNIFORM (readfirstlane-forced SGPR base) -> scalar
// s_load broadcast, no ds_bpermute.
// ---------------------------------------------------------------------------
__global__ __launch_bounds__(256) void k_spmm16(const uint2* __restrict__ edges,
                                                const int* __restrict__ rs,
                                                const unsigned short* __restrict__ x16,
                                                unsigned short* __restrict__ y16) {
    int wid  = (blockIdx.x * 256 + threadIdx.x) >> 6;
    int lane = threadIdx.x & 63;
    if (wid >= N_NODES) return;
    int start = __builtin_amdgcn_readfirstlane(rs[wid]);
    int end   = __builtin_amdgcn_readfirstlane(rs[wid + 1]);
    const unsigned short* xl = x16 + lane;
    float s = 0.0f;
    #pragma unroll 8
    for (int j = start; j < end; ++j) {
        uint2 e = edges[j];                    // uniform addr -> s_load bcast
        s += __uint_as_float(e.y) * bf2f(xl[(int)e.x << 6]);
    }
    y16[(wid << 6) + lane] = f2bf(s);
}

// ---------------------------------------------------------------------------
__global__ void k_zero_loss(float* p) {
    if (blockIdx.x == 0 && threadIdx.x == 0) *p = 0.0f;
}

// ---------------------------------------------------------------------------
// final: per-row  e = (ego_f32 + s1 + s2 + s3)/4 ; h = W1 e + b1 ;
//        g = W2 h + b2 ; out_row = g ; loss += ||g - e||^2
// ---------------------------------------------------------------------------
__global__ __launch_bounds__(256) void k_mlp_loss(const float* __restrict__ ue,
                                                  const float* __restrict__ ie,
                                                  const unsigned short* __restrict__ s1,
                                                  const unsigned short* __restrict__ s2,
                                                  const unsigned short* __restrict__ s3,
                                                  float* __restrict__ out,
                                                  const float* __restrict__ w1,
                                                  const float* __restrict__ b1,
                                                  const float* __restrict__ w2,
                                                  const float* __restrict__ b2,
                                                  float* __restrict__ loss) {
    __shared__ float sw1[RDIM][DIM];
    __shared__ float sw2[DIM][RDIM];
    __shared__ float sb1[RDIM];
    __shared__ float sb2[DIM];

    for (int i = threadIdx.x; i < RDIM * DIM; i += 256) sw1[i / DIM][i % DIM] = w1[i];
    for (int i = threadIdx.x; i < DIM * RDIM; i += 256) sw2[i / RDIM][i % RDIM] = w2[i];
    if (threadIdx.x < RDIM) sb1[threadIdx.x] = b1[threadIdx.x];
    if (threadIdx.x < DIM)  sb2[threadIdx.x] = b2[threadIdx.x];
    __syncthreads();

    int r = blockIdx.x * 256 + threadIdx.x;
    float lsum = 0.0f;
    if (r < N_NODES) {
        const float* ego = (r < N_USERS) ? (ue + (size_t)r * DIM)
                                         : (ie + (size_t)(r - N_USERS) * DIM);
        float e[DIM];
        {
            const float4*  e4 = (const float4*)ego;
            const ushort4* p1 = (const ushort4*)(s1 + ((size_t)r << 6));
            const ushort4* p2 = (const ushort4*)(s2 + ((size_t)r << 6));
            const ushort4* p3 = (const ushort4*)(s3 + ((size_t)r << 6));
            #pragma unroll
            for (int q = 0; q < DIM / 4; ++q) {
                float4 v = e4[q];
                ushort4 a = p1[q], b = p2[q], c = p3[q];
                e[4 * q + 0] = 0.25f * (v.x + bf2f(a.x) + bf2f(b.x) + bf2f(c.x));
                e[4 * q + 1] = 0.25f * (v.y + bf2f(a.y) + bf2f(b.y) + bf2f(c.y));
                e[4 * q + 2] = 0.25f * (v.z + bf2f(a.z) + bf2f(b.z) + bf2f(c.z));
                e[4 * q + 3] = 0.25f * (v.w + bf2f(a.w) + bf2f(b.w) + bf2f(c.w));
            }
        }
        float h[RDIM];
        #pragma unroll
        for (int j = 0; j < RDIM; ++j) {
            float s = sb1[j];
            #pragma unroll
            for (int d = 0; d < DIM; ++d) s += sw1[j][d] * e[d];
            h[j] = s;
        }
        float4* rowp = (float4*)(out + ((size_t)r << 6));
        #pragma unroll
        for (int q = 0; q < DIM / 4; ++q) {
            float g[4];
            #pragma unroll
            for (int m = 0; m < 4; ++m) {
                int k = 4 * q + m;
                float s = sb2[k];
                #pragma unroll
                for (int j = 0; j < RDIM; ++j) s += sw2[k][j] * h[j];
                g[m] = s;
                float df = s - e[k];
                lsum += df * df;
            }
            float4 v;
            v.x = g[0]; v.y = g[1]; v.z = g[2]; v.w = g[3];
            rowp[q] = v;
        }
    }

    #pragma unroll
    for (int off = 32; off > 0; off >>= 1) lsum += __shfl_down(lsum, off);
    __shared__ float wsum[4];
    if ((threadIdx.x & 63) == 0) wsum[threadIdx.x >> 6] = lsum;
    __syncthreads();
    if (threadIdx.x == 0) {
        atomicAdd(loss, wsum[0] + wsum[1] + wsum[2] + wsum[3]);
    }
}

// ---------------------------------------------------------------------------
extern "C" void kernel_launch(void* const* d_in, const int* in_sizes, int n_in,
                              void* d_out, int out_size, void* d_ws, size_t ws_size,
                              hipStream_t stream) {
    const int*   rows = (const int*)d_in[0];
    const int*   cols = (const int*)d_in[1];
    const float* vals = (const float*)d_in[2];
    const float* ue   = (const float*)d_in[3];
    const float* ie   = (const float*)d_in[4];
    const float* w1   = (const float*)d_in[5];
    const float* b1   = (const float*)d_in[6];
    const float* w2   = (const float*)d_in[7];
    const float* b2   = (const float*)d_in[8];
    float* out = (float*)d_out;

    // workspace layout (~116 MB):
    //   A: 38.4 MB  -> s2 (19.2) + s3 (19.2)            [bf16 stages]
    //   B: 38.4 MB  -> partition tmp, then ego0 + s1    [aliased]
    //   C: 38.4 MB  -> edges
    unsigned short* regA = (unsigned short*)d_ws;              // EMB_TOT*2 shorts
    unsigned short* regB = regA + 2 * EMB_TOT;                 // EMB_TOT*2 shorts
    uint2* tmp   = (uint2*)regB;
    uint2* edges = (uint2*)(regB + 2 * EMB_TOT);               // 38.4 MB
    int*   hist  = (int*)(edges + NNZ_E);                      // BPART*NB
    int*   btot  = hist + BPART * NB;                          // NB
    int*   base  = btot + NB;                                  // NB+1
    int*   rs    = base + NB + 1;                              // N_NODES+1

    unsigned short* ego0 = regB;                 // 19.2 MB
    unsigned short* s1   = regB + EMB_TOT;       // 19.2 MB
    unsigned short* s2   = regA;                 // 19.2 MB
    unsigned short* s3   = regA + EMB_TOT;       // 19.2 MB

    const int VEC_BLOCKS  = (EMB_TOT / 4 + 255) / 256;   // 9375
    const int SPMM_BLOCKS = (N_NODES * 64 + 255) / 256;

    // ---- CSR build: deterministic two-level partition, no global atomics ----
    k_hist<<<BPART, TPART, 0, stream>>>(rows, hist);
    k_btot<<<(NB + 255) / 256, 256, 0, stream>>>(hist, btot);
    k_bsum<<<1, 1024, 0, stream>>>(btot, base, rs);
    k_off<<<(NB + 255) / 256, 256, 0, stream>>>(hist, base);
    k_part<<<BPART, TPART, 0, stream>>>(rows, cols, vals, hist, tmp);
    k_sortbkt<<<NB, 512, 0, stream>>>(tmp, base, edges, rs);

    // ---- ego0 (bf16) after tmp is dead ----
    k_init16<<<VEC_BLOCKS, 256, 0, stream>>>((const float4*)ue, (const float4*)ie,
                                             (ushort4*)ego0);

    // ---- 3 propagation layers, bf16 stages, no acc RMW ----
    k_spmm16<<<SPMM_BLOCKS, 256, 0, stream>>>(edges, rs, ego0, s1);
    k_spmm16<<<SPMM_BLOCKS, 256, 0, stream>>>(edges, rs, s1, s2);
    k_spmm16<<<SPMM_BLOCKS, 256, 0, stream>>>(edges, rs, s2, s3);

    k_zero_loss<<<1, 64, 0, stream>>>(out + EMB_TOT);
    k_mlp_loss<<<(N_NODES + 255) / 256, 256, 0, stream>>>(ue, ie, s1, s2, s3,
                                                          out, w1, b1, w2, b2,
                                                          out + EMB_TOT);
}